// Round 13
// baseline (200.386 us; speedup 1.0000x reference)
//
#include <hip/hip_runtime.h>

// IntraGraphAttention: N=50000, E=1.6M, D=128, H=2, C=32. All floats fp32.
// R19: k_final wave-MLP x2 -- 4-way dst concurrency (dl = ws+8c, c=0..3;
// two outer iters): 16 h-row gathers in flight per wave (R18 pairing had 8;
// VALUBusy 37% @ 45% occ showed waves stalled on gather latency 2/3 of the
// time). __launch_bounds__(512,6) caps VGPR ~85 to keep 3 blocks/CU.
// Also dropped the st[] LDS staging: count + rank-scatter both read bufA
// (2nd read L2-hot), saving 2048 ds_write/read per block and 10.5KB LDS.
// Front end unchanged from R18 (split A/B sort blocks, balanced k_fused).

typedef unsigned int u32;
typedef unsigned short u16;

#define SLOTS2 2624     // per-64-node-bucket capacity: mean 2048 (+12.7 sigma)
#define NB2_MAX 800
#define EPB 4096        // edges per sort block

#define XS 136          // bf16 LDS row stride (128 k + 8 pad)
#define CS 68           // fp32 LDS row stride for C staging

#define SMEM_F 34816    // union: node 34816, sort 27008

typedef __attribute__((ext_vector_type(8))) short short8;
typedef __attribute__((ext_vector_type(4))) float float4v;

__device__ __forceinline__ u16 f2bf(float f) {
    union { float f; u32 u; } v; v.f = f;
    u32 r = v.u + 0x7fffu + ((v.u >> 16) & 1u);   // RNE
    return (u16)(r >> 16);
}
__device__ __forceinline__ float bf2f(u16 u) {
    union { u32 i; float f; } v; v.i = ((u32)u) << 16; return v.f;
}
__device__ __forceinline__ float bf_lo(u32 u) {
    union { u32 i; float f; } v; v.i = u << 16; return v.f;
}
__device__ __forceinline__ float bf_hi(u32 u) {
    union { u32 i; float f; } v; v.i = u & 0xFFFF0000u; return v.f;
}
__device__ __forceinline__ void bf_split(float v, short& hi, short& lo) {
    u16 h = f2bf(v);
    float hf = bf2f(h);
    hi = (short)h;
    lo = (short)f2bf(v - hf);
}

// ---------------------------------------------------------------- k_prep
// Zero bucket cursors + build W bf16 hi/lo in fragment-linear layout.
__global__ void k_prep(const float* __restrict__ Wm,
                       short* __restrict__ Whf, short* __restrict__ Wlf,
                       int* cursA, int* cursB)
{
    int t = threadIdx.x;    // 1 block x 256
    for (int i = t; i < NB2_MAX; i += 256) { cursA[i] = 0; cursB[i] = 0; }
    for (int p = t; p < 1024; p += 256) {
        int frag = p >> 6, l = p & 63;
        int ks = frag >> 2, nt = frag & 3;
        int q = l >> 4, m = l & 15;
        int f = nt * 16 + m;
#pragma unroll
        for (int j = 0; j < 8; ++j) {
            int k = ks * 32 + q * 8 + j;
            float wv = Wm[k * 64 + f];
            short hi, lo; bf_split(wv, hi, lo);
            Whf[p * 8 + j] = hi;
            Wlf[p * 8 + j] = lo;
        }
    }
}

// ---------------------------------------------------------------- node body
// Block = 64 nodes. MFMA 16x16x32 bf16, bf16x3 split precision.
static __device__ __forceinline__ void node_body(
    char* smem, int nb_id,
    const float* __restrict__ x,
    const short* __restrict__ Whf, const short* __restrict__ Wlf,
    const float* __restrict__ att_s, const float* __restrict__ att_d,
    u32* __restrict__ hb32, float* __restrict__ a_src, float* __restrict__ a_dst,
    int nN)
{
    short* Ah = (short*)smem;              // 17408 B
    short* Al = (short*)(smem + 17408);    // 17408 B
    float* Cl = (float*)Ah;                // reused post-MFMA

    int t = threadIdx.x;
    int n0 = nb_id * 64;

    for (int j = 0; j < 8; ++j) {    // stage elu(x) bf16 hi/lo
        int idx = t + 256 * j;
        int r = idx >> 5, c4 = idx & 31;
        int gn = n0 + r;
        float4 xv = make_float4(0.f, 0.f, 0.f, 0.f);
        if (gn < nN) xv = ((const float4*)x)[(size_t)gn * 32 + c4];
        float e[4];
        e[0] = xv.x > 0.f ? xv.x : __expf(xv.x) - 1.f;
        e[1] = xv.y > 0.f ? xv.y : __expf(xv.y) - 1.f;
        e[2] = xv.z > 0.f ? xv.z : __expf(xv.z) - 1.f;
        e[3] = xv.w > 0.f ? xv.w : __expf(xv.w) - 1.f;
        short h4[4], l4[4];
#pragma unroll
        for (int i = 0; i < 4; ++i) bf_split(e[i], h4[i], l4[i]);
        *(short4*)&Ah[r * XS + c4 * 4] = make_short4(h4[0], h4[1], h4[2], h4[3]);
        *(short4*)&Al[r * XS + c4 * 4] = make_short4(l4[0], l4[1], l4[2], l4[3]);
    }
    __syncthreads();

    {   // MFMA: wave w -> nodes [16w,16w+16)
        int w = t >> 6, l = t & 63;
        int q = l >> 4, m = l & 15;
        int arow = w * 16 + m;
        float4v acc[4] = {};
#pragma unroll
        for (int ks = 0; ks < 4; ++ks) {
            int k0 = ks * 32 + q * 8;
            short8 ah = *(const short8*)&Ah[arow * XS + k0];
            short8 al = *(const short8*)&Al[arow * XS + k0];
#pragma unroll
            for (int nt = 0; nt < 4; ++nt) {
                short8 bh = *(const short8*)&Whf[((ks * 4 + nt) * 64 + l) * 8];
                short8 bl = *(const short8*)&Wlf[((ks * 4 + nt) * 64 + l) * 8];
                acc[nt] = __builtin_amdgcn_mfma_f32_16x16x32_bf16(ah, bh, acc[nt], 0, 0, 0);
                acc[nt] = __builtin_amdgcn_mfma_f32_16x16x32_bf16(ah, bl, acc[nt], 0, 0, 0);
                acc[nt] = __builtin_amdgcn_mfma_f32_16x16x32_bf16(al, bh, acc[nt], 0, 0, 0);
            }
        }
        __syncthreads();
        // C/D layout: col = lane&15, row = quad*4 + reg
#pragma unroll
        for (int nt = 0; nt < 4; ++nt)
#pragma unroll
            for (int r = 0; r < 4; ++r)
                Cl[(w * 16 + q * 4 + r) * CS + nt * 16 + m] = acc[nt][r];
    }
    __syncthreads();

    {   // epilogue: thread t -> node t>>2, feature quarter (t&3)*16
        int nl = t >> 2, fq = t & 3;
        int gn = n0 + nl;
        float ps = 0.f, pd = 0.f;
        if (gn < nN) {
            float hv[16];
#pragma unroll
            for (int i = 0; i < 16; ++i) {
                int f = fq * 16 + i;
                hv[i] = Cl[nl * CS + f];
                ps = fmaf(hv[i], att_s[f], ps);
                pd = fmaf(hv[i], att_d[f], pd);
            }
#pragma unroll
            for (int i = 0; i < 8; ++i) {
                u32 pk = ((u32)f2bf(hv[2 * i + 1]) << 16) | (u32)f2bf(hv[2 * i]);
                hb32[(size_t)gn * 32 + fq * 8 + i] = pk;
            }
        }
        float ps2 = ps + __shfl_xor(ps, 1, 64);
        float pd2 = pd + __shfl_xor(pd, 1, 64);
        if (gn < nN && (fq & 1) == 0) {
            a_src[2 * gn + (fq >> 1)] = ps2;
            a_dst[2 * gn + (fq >> 1)] = pd2;
        }
    }
}

// ---------------------------------------------------------------- sort body
// ONE LDS counting sort over 782 64-node buckets (27KB).
// sideB=0 (dst): arr = bucket(10)<<22 | dstlocal(6)<<16 | src(16) -> bufA
// sideB=1 (src): arr = bucket(10)<<22 | srclocal(6)<<16 | w16     -> bufB
static __device__ __forceinline__ void sort_body(
    char* smem, int pa_id, int sideB,
    const int* __restrict__ ei, const float* __restrict__ wgt,
    int* curs, u32* buf, int E, int nb2)
{
    u32* arr  = (u32*)smem;                   // 16384
    int* cnt  = (int*)(smem + 16384);         // 3200
    int* lofs = (int*)(smem + 19584);         // 3200
    int* bas  = (int*)(smem + 22784);         // 3200
    int* part = (int*)(smem + 25984);         // 1024 -> 27008 total

    int t = threadIdx.x;
    int base = pa_id * EPB;
    int nv = min(EPB, E - base);
    int key[16]; u32 pay[16];
#pragma unroll
    for (int k = 0; k < 16; ++k) {
        int e = base + k * 256 + t;
        if (e < E) {
            if (sideB) {
                key[k] = ei[e];
                u32 wq = (u32)(wgt[e] * 65536.f);
                if (wq > 0xFFFFu) wq = 0xFFFFu;
                pay[k] = wq;
            } else {
                key[k] = ei[E + e];
                pay[k] = (u32)ei[e];
            }
        } else { key[k] = -1; pay[k] = 0u; }
    }

    for (int b = t; b < nb2; b += 256) cnt[b] = 0;
    __syncthreads();
#pragma unroll
    for (int k = 0; k < 16; ++k)
        if (key[k] >= 0) atomicAdd(&cnt[key[k] >> 6], 1);
    __syncthreads();
    // reserve global ranges (one atomic per nonzero bucket)
    for (int b = t; b < nb2; b += 256) {
        int c = cnt[b];
        if (c > 0) bas[b] = atomicAdd(&curs[b], c);
    }
    __syncthreads();
    // exclusive scan over buckets (thread t owns buckets 4t..4t+3)
    {
        int c[4]; int s = 0;
#pragma unroll
        for (int i = 0; i < 4; ++i) {
            int bb = 4 * t + i;
            c[i] = (bb < nb2) ? cnt[bb] : 0;
            s += c[i];
        }
        part[t] = s;
        __syncthreads();
        for (int off = 1; off < 256; off <<= 1) {
            int v = (t >= off) ? part[t - off] : 0;
            __syncthreads();
            part[t] += v;
            __syncthreads();
        }
        int excl = part[t] - s;
#pragma unroll
        for (int i = 0; i < 4; ++i) {
            int bb = 4 * t + i;
            if (bb < nb2) lofs[bb] = excl;
            excl += c[i];
        }
    }
    __syncthreads();
    // reset counters for rank pass
    for (int b = t; b < nb2; b += 256) cnt[b] = 0;
    __syncthreads();
    // rank + scatter into LDS (bucket-sorted order)
#pragma unroll
    for (int k = 0; k < 16; ++k) {
        if (key[k] >= 0) {
            int bk = key[k] >> 6;
            int r = lofs[bk] + atomicAdd(&cnt[bk], 1);
            arr[r] = ((u32)bk << 22) | ((u32)(key[k] & 63) << 16) | pay[k];
        }
    }
    __syncthreads();
    // coalesced chunk writes
    for (int i = t; i < nv; i += 256) {
        u32 va = arr[i];
        int bk = va >> 22;
        int g = bas[bk] + (i - lofs[bk]);
        if (g < SLOTS2) buf[(size_t)bk * SLOTS2 + g] = va & 0x3FFFFFu;
    }
}

// ---------------------------------------------------------------- k_fused
// Block map: groups of 4 = [A-sort(g), node, B-sort(g), node]; uniform
// block durations -> balanced CU load. Union LDS 34.8KB -> 4 blocks/CU.
__global__ __launch_bounds__(256) void k_fused(
    const float* __restrict__ x,
    const short* __restrict__ Whf, const short* __restrict__ Wlf,
    const float* __restrict__ att_s, const float* __restrict__ att_d,
    u32* __restrict__ hb32, float* __restrict__ a_src, float* __restrict__ a_dst,
    const int* __restrict__ ei, const float* __restrict__ wgt,
    int* cursA, int* cursB, u32* bufA, u32* bufB,
    int E, int nb2, int nblkA, int nN)
{
    __shared__ __align__(16) char smem[SMEM_F];
    int bid = blockIdx.x;
    int g = bid >> 2, r = bid & 3;
    if (g < nblkA && r == 0) {
        sort_body(smem, g, 0, ei, wgt, cursA, bufA, E, nb2);
    } else if (g < nblkA && r == 2) {
        sort_body(smem, g, 1, ei, wgt, cursB, bufB, E, nb2);
    } else {
        int sortBefore = (g < nblkA) ? (2 * g + (r >= 1 ? 1 : 0) + (r >= 3 ? 1 : 0))
                                     : 2 * nblkA;
        node_body(smem, bid - sortBefore, x, Whf, Wlf, att_s, att_d,
                  hb32, a_src, a_dst, nN);
    }
}

// ---------------------------------------------------------------- k_final
// One 512-thread block per 64-node bucket (782 blocks). Phase 1-3: count
// from bufA, scan, rank-scatter into st2 (bufA re-read, L2-hot) + bufB
// weight-mean reduce. Phase 4: 4-WAY dst concurrency -- wave ws runs dsts
// dl = ws+8c (c=0..3) jointly, then +32: 16 h-row gathers in flight/wave.
__global__ __launch_bounds__(512, 6) void k_final(
    const u32* __restrict__ hb32,
    const float* __restrict__ a_src, const float* __restrict__ a_dst,
    const u32* __restrict__ bufA, const int* __restrict__ cursA,
    const u32* __restrict__ bufB, const int* __restrict__ cursB,
    const float* __restrict__ bias, const float* __restrict__ esc,
    float* __restrict__ out, int nN)
{
    __shared__ u16 st2[SLOTS2];        // grouped si by dst
    __shared__ int ldeg[64], lscan[64], lcur[64];
    __shared__ int usum[64], ucnt[64];

    int b = blockIdx.x, t = threadIdx.x;
    int n0 = b << 6;
    int nA = cursA[b]; if (nA > SLOTS2) nA = SLOTS2;
    int nB = cursB[b]; if (nB > SLOTS2) nB = SLOTS2;

    if (t < 64) { ldeg[t] = 0; lcur[t] = 0; usum[t] = 0; ucnt[t] = 0; }
    __syncthreads();
    for (int i = t; i < nA; i += 512) {
        u32 v = bufA[(size_t)b * SLOTS2 + i];
        atomicAdd(&ldeg[v >> 16], 1);          // v has 22 bits -> v>>16 = dl
    }
    for (int i = t; i < nB; i += 512) {
        u32 v = bufB[(size_t)b * SLOTS2 + i];
        atomicAdd(&usum[v >> 16], (int)(v & 0xFFFFu));
        atomicAdd(&ucnt[v >> 16], 1);
    }
    __syncthreads();
    // exclusive scan of ldeg (64 entries)
    if (t < 64) lscan[t] = ldeg[t];
    __syncthreads();
    for (int off = 1; off < 64; off <<= 1) {
        int v = 0;
        if (t < 64 && t >= off) v = lscan[t - off];
        __syncthreads();
        if (t < 64) lscan[t] += v;
        __syncthreads();
    }
    if (t < 64) lscan[t] -= ldeg[t];
    __syncthreads();
    // rank-scatter grouped si into st2 (bufA re-read, L2-resident)
    for (int i = t; i < nA; i += 512) {
        u32 v = bufA[(size_t)b * SLOTS2 + i];
        int dl = v >> 16;
        int pos = lscan[dl] + atomicAdd(&lcur[dl], 1);
        st2[pos] = (u16)(v & 0xFFFFu);
    }
    __syncthreads();

    // phase 4: 4-way concurrent dst accumulation
    int ws = t >> 6, lane = t & 63;
    int q = lane >> 4, fl = lane & 15, head = fl >> 3;
    const uint2* hb2 = (const uint2*)hb32;
    float escv = esc[0];
    float sf = 0.1f / (1.f + __expf(-escv));
    float4 bb = ((const float4*)bias)[fl];

    for (int j = 0; j < 2; ++j) {
        int dlb = ws + 32 * j;
        int gn4[4], beg4[4], cnt4[4];
        float adx[4], ady[4], e0s[4], e1s[4], ds4[4];
        float ac0[4], ac1[4], ac2[4], ac3[4];
        bool val[4];
#pragma unroll
        for (int c = 0; c < 4; ++c) {
            int dl = dlb + 8 * c;
            int g = n0 + dl;
            gn4[c] = g;
            val[c] = (g < nN);
            beg4[c] = lscan[dl];
            cnt4[c] = val[c] ? ldeg[dl] : 0;
            float2 adv = make_float2(0.f, 0.f), asv = make_float2(0.f, 0.f);
            if (val[c]) {
                adv = ((const float2*)a_dst)[g];
                asv = ((const float2*)a_src)[g];
            }
            adx[c] = adv.x; ady[c] = adv.y;
            float t0 = asv.x + adv.x; t0 = t0 > 0.f ? t0 : 0.2f * t0;
            float t1 = asv.y + adv.y; t1 = t1 > 0.f ? t1 : 0.2f * t1;
            e0s[c] = __expf(t0); e1s[c] = __expf(t1);
            ac0[c] = ac1[c] = ac2[c] = ac3[c] = 0.f;
            ds4[c] = 0.f;
            if (q == 0 && val[c]) {            // self-loop: ONE group only
                float eself = head ? e1s[c] : e0s[c];
                uint2 hs = hb2[(size_t)g * 16 + fl];
                ac0[c] = eself * bf_lo(hs.x);
                ac1[c] = eself * bf_hi(hs.x);
                ac2[c] = eself * bf_lo(hs.y);
                ac3[c] = eself * bf_hi(hs.y);
            }
        }
        int nwin = 0;
#pragma unroll
        for (int c = 0; c < 4; ++c) {
            int nw = (cnt4[c] + 63) >> 6;
            if (nw > nwin) nwin = nw;
        }
        for (int w = 0; w < nwin; ++w) {
            int b0 = w << 6;
            u32 si4[4]; float we0[4], we1[4]; int wn4[4];
#pragma unroll
            for (int c = 0; c < 4; ++c) {
                si4[c] = (u32)n0; we0[c] = 0.f; we1[c] = 0.f; wn4[c] = 0;
                if (b0 < cnt4[c]) {
                    int wn = cnt4[c] - b0; if (wn > 64) wn = 64;
                    wn4[c] = wn;
                    if (lane < wn) {
                        si4[c] = (u32)st2[beg4[c] + b0 + lane];
                        float2 ap = ((const float2*)a_src)[si4[c]];
                        float v0 = ap.x + adx[c]; v0 = v0 > 0.f ? v0 : 0.2f * v0;
                        float v1 = ap.y + ady[c]; v1 = v1 > 0.f ? v1 : 0.2f * v1;
                        we0[c] = __expf(v0); we1[c] = __expf(v1);
                    }
                }
            }
            int wmax = 0;
#pragma unroll
            for (int c = 0; c < 4; ++c) if (wn4[c] > wmax) wmax = wn4[c];
            int iters = (wmax + 3) >> 2;
#pragma unroll 2
            for (int k = 0; k < iters; ++k) {
                int e = 4 * k + q;             // pad lanes carry w=0
#pragma unroll
                for (int c = 0; c < 4; ++c) {
                    u32 rsi = __shfl(si4[c], e, 64);
                    uint2 hv = hb2[(size_t)rsi * 16 + fl];
                    float w0 = __shfl(we0[c], e, 64);
                    float w1 = __shfl(we1[c], e, 64);
                    float wv = head ? w1 : w0;
                    ds4[c] += wv;
                    ac0[c] = fmaf(wv, bf_lo(hv.x), ac0[c]);
                    ac1[c] = fmaf(wv, bf_hi(hv.x), ac1[c]);
                    ac2[c] = fmaf(wv, bf_lo(hv.y), ac2[c]);
                    ac3[c] = fmaf(wv, bf_hi(hv.y), ac3[c]);
                }
            }
        }
        // reduce over the 4 quarter-groups + epilogue
#pragma unroll
        for (int c = 0; c < 4; ++c) {
            ds4[c] += __shfl_xor(ds4[c], 16, 64); ds4[c] += __shfl_xor(ds4[c], 32, 64);
            ac0[c] += __shfl_xor(ac0[c], 16, 64); ac0[c] += __shfl_xor(ac0[c], 32, 64);
            ac1[c] += __shfl_xor(ac1[c], 16, 64); ac1[c] += __shfl_xor(ac1[c], 32, 64);
            ac2[c] += __shfl_xor(ac2[c], 16, 64); ac2[c] += __shfl_xor(ac2[c], 32, 64);
            ac3[c] += __shfl_xor(ac3[c], 16, 64); ac3[c] += __shfl_xor(ac3[c], 32, 64);
            if (q == 0 && val[c]) {
                int dl = dlb + 8 * c;
                float den = (head ? e1s[c] : e0s[c]) + ds4[c];
                float inv = 1.f / den;
                float cntf = (float)ucnt[dl];
                float nw = ((float)usum[dl] * (1.f / 65536.f)) / fmaxf(cntf, 1.f);
                nw = fminf(fmaxf(nw, 0.2f), 5.f);
                float en = sf * (nw - 1.f);
                float4 o;
                o.x = ac0[c] * inv + bb.x + en;
                o.y = ac1[c] * inv + bb.y + en;
                o.z = ac2[c] * inv + bb.z + en;
                o.w = ac3[c] * inv + bb.w + en;
                ((float4*)out)[(size_t)gn4[c] * 16 + fl] = o;
            }
        }
    }
}

// ---------------------------------------------------------------- launch
extern "C" void kernel_launch(void* const* d_in, const int* in_sizes, int n_in,
                              void* d_out, int out_size, void* d_ws, size_t ws_size,
                              hipStream_t stream)
{
    const float* x     = (const float*)d_in[0];
    const int*   ei    = (const int*)d_in[1];
    const float* wgt   = (const float*)d_in[2];
    const float* Wm    = (const float*)d_in[3];
    const float* att_s = (const float*)d_in[4];
    const float* att_d = (const float*)d_in[5];
    const float* bias  = (const float*)d_in[6];
    const float* esc   = (const float*)d_in[7];
    float* out = (float*)d_out;

    int nN = in_sizes[0] / 128;
    int E  = in_sizes[2];
    int NB2 = (nN + 63) / 64;         // 782 buckets of 64 nodes

    char* p = (char*)d_ws;
    auto alloc = [&](size_t bytes) -> char* {
        char* r = p; p += (bytes + 255) & ~(size_t)255; return r;
    };
    u32*   hb32  = (u32*)  alloc((size_t)nN * 32 * 4);
    float* a_src = (float*)alloc((size_t)nN * 2 * 4);
    float* a_dst = (float*)alloc((size_t)nN * 2 * 4);
    short* Whf   = (short*)alloc(16 * 64 * 8 * 2);
    short* Wlf   = (short*)alloc(16 * 64 * 8 * 2);
    int*   cursA = (int*)  alloc(NB2_MAX * 4);
    int*   cursB = (int*)  alloc(NB2_MAX * 4);
    u32*   bufA  = (u32*)  alloc((size_t)NB2 * SLOTS2 * 4);
    u32*   bufB  = (u32*)  alloc((size_t)NB2 * SLOTS2 * 4);

    int nblkA = (E + EPB - 1) / EPB;
    int nblkN = (nN + 63) / 64;
    int nblkF = 2 * nblkA + nblkN;

    k_prep<<<dim3(1), dim3(256), 0, stream>>>(Wm, Whf, Wlf, cursA, cursB);
    k_fused<<<dim3(nblkF), dim3(256), 0, stream>>>(x, Whf, Wlf, att_s, att_d,
                                                   hb32, a_src, a_dst,
                                                   ei, wgt, cursA, cursB, bufA, bufB,
                                                   E, NB2, nblkA, nN);
    k_final<<<dim3(NB2), dim3(512), 0, stream>>>(hb32, a_src, a_dst, bufA, cursA,
                                                 bufB, cursB, bias, esc, out, nN);
}

// Round 14
// 170.738 us; speedup vs baseline: 1.1736x; 1.1736x over previous
//
#include <hip/hip_runtime.h>

// IntraGraphAttention: N=50000, E=1.6M, D=128, H=2, C=32. All floats fp32.
// R20: REVERT to R18 (measured 170.1us best). R19's 4-way dst concurrency
// under __launch_bounds__(512,6) forced register spills (WRITE_SIZE 12.5->
// 56MB, FETCH +20MB, k_final 52->85us) -- occupancy-preserving VGPR cap
// can't hold 4-way state; 2-way pairing (VGPR 32, no spill) is the wave-MLP
// sweet spot. This is R18 verbatim: split A/B sort blocks interleaved with
// node blocks (balanced k_fused), dst-paired k_final with in-loop dsum.

typedef unsigned int u32;
typedef unsigned short u16;

#define SLOTS2 2624     // per-64-node-bucket capacity: mean 2048 (+12.7 sigma)
#define NB2_MAX 800
#define EPB 4096        // edges per sort block

#define XS 136          // bf16 LDS row stride (128 k + 8 pad)
#define CS 68           // fp32 LDS row stride for C staging

#define SMEM_F 34816    // union: node 34816, sort 27008

typedef __attribute__((ext_vector_type(8))) short short8;
typedef __attribute__((ext_vector_type(4))) float float4v;

__device__ __forceinline__ u16 f2bf(float f) {
    union { float f; u32 u; } v; v.f = f;
    u32 r = v.u + 0x7fffu + ((v.u >> 16) & 1u);   // RNE
    return (u16)(r >> 16);
}
__device__ __forceinline__ float bf2f(u16 u) {
    union { u32 i; float f; } v; v.i = ((u32)u) << 16; return v.f;
}
__device__ __forceinline__ float bf_lo(u32 u) {
    union { u32 i; float f; } v; v.i = u << 16; return v.f;
}
__device__ __forceinline__ float bf_hi(u32 u) {
    union { u32 i; float f; } v; v.i = u & 0xFFFF0000u; return v.f;
}
__device__ __forceinline__ void bf_split(float v, short& hi, short& lo) {
    u16 h = f2bf(v);
    float hf = bf2f(h);
    hi = (short)h;
    lo = (short)f2bf(v - hf);
}

// ---------------------------------------------------------------- k_prep
// Zero bucket cursors + build W bf16 hi/lo in fragment-linear layout.
__global__ void k_prep(const float* __restrict__ Wm,
                       short* __restrict__ Whf, short* __restrict__ Wlf,
                       int* cursA, int* cursB)
{
    int t = threadIdx.x;    // 1 block x 256
    for (int i = t; i < NB2_MAX; i += 256) { cursA[i] = 0; cursB[i] = 0; }
    for (int p = t; p < 1024; p += 256) {
        int frag = p >> 6, l = p & 63;
        int ks = frag >> 2, nt = frag & 3;
        int q = l >> 4, m = l & 15;
        int f = nt * 16 + m;
#pragma unroll
        for (int j = 0; j < 8; ++j) {
            int k = ks * 32 + q * 8 + j;
            float wv = Wm[k * 64 + f];
            short hi, lo; bf_split(wv, hi, lo);
            Whf[p * 8 + j] = hi;
            Wlf[p * 8 + j] = lo;
        }
    }
}

// ---------------------------------------------------------------- node body
// Block = 64 nodes. MFMA 16x16x32 bf16, bf16x3 split precision.
static __device__ __forceinline__ void node_body(
    char* smem, int nb_id,
    const float* __restrict__ x,
    const short* __restrict__ Whf, const short* __restrict__ Wlf,
    const float* __restrict__ att_s, const float* __restrict__ att_d,
    u32* __restrict__ hb32, float* __restrict__ a_src, float* __restrict__ a_dst,
    int nN)
{
    short* Ah = (short*)smem;              // 17408 B
    short* Al = (short*)(smem + 17408);    // 17408 B
    float* Cl = (float*)Ah;                // reused post-MFMA

    int t = threadIdx.x;
    int n0 = nb_id * 64;

    for (int j = 0; j < 8; ++j) {    // stage elu(x) bf16 hi/lo
        int idx = t + 256 * j;
        int r = idx >> 5, c4 = idx & 31;
        int gn = n0 + r;
        float4 xv = make_float4(0.f, 0.f, 0.f, 0.f);
        if (gn < nN) xv = ((const float4*)x)[(size_t)gn * 32 + c4];
        float e[4];
        e[0] = xv.x > 0.f ? xv.x : __expf(xv.x) - 1.f;
        e[1] = xv.y > 0.f ? xv.y : __expf(xv.y) - 1.f;
        e[2] = xv.z > 0.f ? xv.z : __expf(xv.z) - 1.f;
        e[3] = xv.w > 0.f ? xv.w : __expf(xv.w) - 1.f;
        short h4[4], l4[4];
#pragma unroll
        for (int i = 0; i < 4; ++i) bf_split(e[i], h4[i], l4[i]);
        *(short4*)&Ah[r * XS + c4 * 4] = make_short4(h4[0], h4[1], h4[2], h4[3]);
        *(short4*)&Al[r * XS + c4 * 4] = make_short4(l4[0], l4[1], l4[2], l4[3]);
    }
    __syncthreads();

    {   // MFMA: wave w -> nodes [16w,16w+16)
        int w = t >> 6, l = t & 63;
        int q = l >> 4, m = l & 15;
        int arow = w * 16 + m;
        float4v acc[4] = {};
#pragma unroll
        for (int ks = 0; ks < 4; ++ks) {
            int k0 = ks * 32 + q * 8;
            short8 ah = *(const short8*)&Ah[arow * XS + k0];
            short8 al = *(const short8*)&Al[arow * XS + k0];
#pragma unroll
            for (int nt = 0; nt < 4; ++nt) {
                short8 bh = *(const short8*)&Whf[((ks * 4 + nt) * 64 + l) * 8];
                short8 bl = *(const short8*)&Wlf[((ks * 4 + nt) * 64 + l) * 8];
                acc[nt] = __builtin_amdgcn_mfma_f32_16x16x32_bf16(ah, bh, acc[nt], 0, 0, 0);
                acc[nt] = __builtin_amdgcn_mfma_f32_16x16x32_bf16(ah, bl, acc[nt], 0, 0, 0);
                acc[nt] = __builtin_amdgcn_mfma_f32_16x16x32_bf16(al, bh, acc[nt], 0, 0, 0);
            }
        }
        __syncthreads();
        // C/D layout: col = lane&15, row = quad*4 + reg
#pragma unroll
        for (int nt = 0; nt < 4; ++nt)
#pragma unroll
            for (int r = 0; r < 4; ++r)
                Cl[(w * 16 + q * 4 + r) * CS + nt * 16 + m] = acc[nt][r];
    }
    __syncthreads();

    {   // epilogue: thread t -> node t>>2, feature quarter (t&3)*16
        int nl = t >> 2, fq = t & 3;
        int gn = n0 + nl;
        float ps = 0.f, pd = 0.f;
        if (gn < nN) {
            float hv[16];
#pragma unroll
            for (int i = 0; i < 16; ++i) {
                int f = fq * 16 + i;
                hv[i] = Cl[nl * CS + f];
                ps = fmaf(hv[i], att_s[f], ps);
                pd = fmaf(hv[i], att_d[f], pd);
            }
#pragma unroll
            for (int i = 0; i < 8; ++i) {
                u32 pk = ((u32)f2bf(hv[2 * i + 1]) << 16) | (u32)f2bf(hv[2 * i]);
                hb32[(size_t)gn * 32 + fq * 8 + i] = pk;
            }
        }
        float ps2 = ps + __shfl_xor(ps, 1, 64);
        float pd2 = pd + __shfl_xor(pd, 1, 64);
        if (gn < nN && (fq & 1) == 0) {
            a_src[2 * gn + (fq >> 1)] = ps2;
            a_dst[2 * gn + (fq >> 1)] = pd2;
        }
    }
}

// ---------------------------------------------------------------- sort body
// ONE LDS counting sort over 782 64-node buckets (27KB).
// sideB=0 (dst): arr = bucket(10)<<22 | dstlocal(6)<<16 | src(16) -> bufA
// sideB=1 (src): arr = bucket(10)<<22 | srclocal(6)<<16 | w16     -> bufB
static __device__ __forceinline__ void sort_body(
    char* smem, int pa_id, int sideB,
    const int* __restrict__ ei, const float* __restrict__ wgt,
    int* curs, u32* buf, int E, int nb2)
{
    u32* arr  = (u32*)smem;                   // 16384
    int* cnt  = (int*)(smem + 16384);         // 3200
    int* lofs = (int*)(smem + 19584);         // 3200
    int* bas  = (int*)(smem + 22784);         // 3200
    int* part = (int*)(smem + 25984);         // 1024 -> 27008 total

    int t = threadIdx.x;
    int base = pa_id * EPB;
    int nv = min(EPB, E - base);
    int key[16]; u32 pay[16];
#pragma unroll
    for (int k = 0; k < 16; ++k) {
        int e = base + k * 256 + t;
        if (e < E) {
            if (sideB) {
                key[k] = ei[e];
                u32 wq = (u32)(wgt[e] * 65536.f);
                if (wq > 0xFFFFu) wq = 0xFFFFu;
                pay[k] = wq;
            } else {
                key[k] = ei[E + e];
                pay[k] = (u32)ei[e];
            }
        } else { key[k] = -1; pay[k] = 0u; }
    }

    for (int b = t; b < nb2; b += 256) cnt[b] = 0;
    __syncthreads();
#pragma unroll
    for (int k = 0; k < 16; ++k)
        if (key[k] >= 0) atomicAdd(&cnt[key[k] >> 6], 1);
    __syncthreads();
    // reserve global ranges (one atomic per nonzero bucket)
    for (int b = t; b < nb2; b += 256) {
        int c = cnt[b];
        if (c > 0) bas[b] = atomicAdd(&curs[b], c);
    }
    __syncthreads();
    // exclusive scan over buckets (thread t owns buckets 4t..4t+3)
    {
        int c[4]; int s = 0;
#pragma unroll
        for (int i = 0; i < 4; ++i) {
            int bb = 4 * t + i;
            c[i] = (bb < nb2) ? cnt[bb] : 0;
            s += c[i];
        }
        part[t] = s;
        __syncthreads();
        for (int off = 1; off < 256; off <<= 1) {
            int v = (t >= off) ? part[t - off] : 0;
            __syncthreads();
            part[t] += v;
            __syncthreads();
        }
        int excl = part[t] - s;
#pragma unroll
        for (int i = 0; i < 4; ++i) {
            int bb = 4 * t + i;
            if (bb < nb2) lofs[bb] = excl;
            excl += c[i];
        }
    }
    __syncthreads();
    // reset counters for rank pass
    for (int b = t; b < nb2; b += 256) cnt[b] = 0;
    __syncthreads();
    // rank + scatter into LDS (bucket-sorted order)
#pragma unroll
    for (int k = 0; k < 16; ++k) {
        if (key[k] >= 0) {
            int bk = key[k] >> 6;
            int r = lofs[bk] + atomicAdd(&cnt[bk], 1);
            arr[r] = ((u32)bk << 22) | ((u32)(key[k] & 63) << 16) | pay[k];
        }
    }
    __syncthreads();
    // coalesced chunk writes
    for (int i = t; i < nv; i += 256) {
        u32 va = arr[i];
        int bk = va >> 22;
        int g = bas[bk] + (i - lofs[bk]);
        if (g < SLOTS2) buf[(size_t)bk * SLOTS2 + g] = va & 0x3FFFFFu;
    }
}

// ---------------------------------------------------------------- k_fused
// Block map: groups of 4 = [A-sort(g), node, B-sort(g), node]; uniform
// block durations -> balanced CU load. Union LDS 34.8KB -> 4 blocks/CU.
__global__ __launch_bounds__(256) void k_fused(
    const float* __restrict__ x,
    const short* __restrict__ Whf, const short* __restrict__ Wlf,
    const float* __restrict__ att_s, const float* __restrict__ att_d,
    u32* __restrict__ hb32, float* __restrict__ a_src, float* __restrict__ a_dst,
    const int* __restrict__ ei, const float* __restrict__ wgt,
    int* cursA, int* cursB, u32* bufA, u32* bufB,
    int E, int nb2, int nblkA, int nN)
{
    __shared__ __align__(16) char smem[SMEM_F];
    int bid = blockIdx.x;
    int g = bid >> 2, r = bid & 3;
    if (g < nblkA && r == 0) {
        sort_body(smem, g, 0, ei, wgt, cursA, bufA, E, nb2);
    } else if (g < nblkA && r == 2) {
        sort_body(smem, g, 1, ei, wgt, cursB, bufB, E, nb2);
    } else {
        int sortBefore = (g < nblkA) ? (2 * g + (r >= 1 ? 1 : 0) + (r >= 3 ? 1 : 0))
                                     : 2 * nblkA;
        node_body(smem, bid - sortBefore, x, Whf, Wlf, att_s, att_d,
                  hb32, a_src, a_dst, nN);
    }
}

// ---------------------------------------------------------------- k_final
// One 512-thread block per 64-node bucket (782 blocks). Phase 1-3: group
// ~2048 edges by dst in LDS (int atomics) + bufB weight-mean reduce.
// Phase 4: DST-PAIRED -- wave ws handles pairs (dl0, dl0+8) for dl0 = ws,
// ws+16, ws+32, ws+48: both dsts' windows processed jointly so their h-row
// gathers interleave (2x memory-level parallelism); in-loop dsum.
__global__ __launch_bounds__(512) void k_final(
    const u32* __restrict__ hb32,
    const float* __restrict__ a_src, const float* __restrict__ a_dst,
    const u32* __restrict__ bufA, const int* __restrict__ cursA,
    const u32* __restrict__ bufB, const int* __restrict__ cursB,
    const float* __restrict__ bias, const float* __restrict__ esc,
    float* __restrict__ out, int nN)
{
    __shared__ u32 st[SLOTS2];         // ungrouped edges (dl<<16 | si)
    __shared__ u16 st2[SLOTS2];        // grouped si by dst
    __shared__ int ldeg[64], lscan[64], lcur[64];
    __shared__ int usum[64], ucnt[64];

    int b = blockIdx.x, t = threadIdx.x;
    int n0 = b << 6;
    int nA = cursA[b]; if (nA > SLOTS2) nA = SLOTS2;
    int nB = cursB[b]; if (nB > SLOTS2) nB = SLOTS2;

    if (t < 64) { ldeg[t] = 0; lcur[t] = 0; usum[t] = 0; ucnt[t] = 0; }
    __syncthreads();
    for (int i = t; i < nA; i += 512) {
        u32 v = bufA[(size_t)b * SLOTS2 + i];
        st[i] = v;
        atomicAdd(&ldeg[v >> 16], 1);          // v has 22 bits -> v>>16 = dl
    }
    for (int i = t; i < nB; i += 512) {
        u32 v = bufB[(size_t)b * SLOTS2 + i];
        atomicAdd(&usum[v >> 16], (int)(v & 0xFFFFu));
        atomicAdd(&ucnt[v >> 16], 1);
    }
    __syncthreads();
    // exclusive scan of ldeg (64 entries)
    if (t < 64) lscan[t] = ldeg[t];
    __syncthreads();
    for (int off = 1; off < 64; off <<= 1) {
        int v = 0;
        if (t < 64 && t >= off) v = lscan[t - off];
        __syncthreads();
        if (t < 64) lscan[t] += v;
        __syncthreads();
    }
    if (t < 64) lscan[t] -= ldeg[t];
    __syncthreads();
    // rank-scatter grouped si into st2
    for (int i = t; i < nA; i += 512) {
        u32 v = st[i];
        int dl = v >> 16;
        int pos = lscan[dl] + atomicAdd(&lcur[dl], 1);
        st2[pos] = (u16)(v & 0xFFFFu);
    }
    __syncthreads();

    // phase 4: paired-dst register accumulation
    int ws = t >> 6, lane = t & 63;
    int q = lane >> 4, fl = lane & 15, head = fl >> 3;
    const uint2* hb2 = (const uint2*)hb32;
    float escv = esc[0];
    float sf = 0.1f / (1.f + __expf(-escv));
    float4 bb = ((const float4*)bias)[fl];

    for (int dl0 = ws; dl0 < 64; dl0 += 16) {
        int dlA = dl0, dlB = dl0 + 8;
        int gnA = n0 + dlA, gnB = n0 + dlB;
        if (gnA >= nN) break;                  // wave-uniform, increasing
        bool vB = (gnB < nN);

        // ---- setup A
        int begA = lscan[dlA], cntA = ldeg[dlA];
        float2 advA = ((const float2*)a_dst)[gnA];
        float2 asvA = ((const float2*)a_src)[gnA];
        float tA0 = asvA.x + advA.x; tA0 = tA0 > 0.f ? tA0 : 0.2f * tA0;
        float tA1 = asvA.y + advA.y; tA1 = tA1 > 0.f ? tA1 : 0.2f * tA1;
        float esA0 = __expf(tA0), esA1 = __expf(tA1);
        float aA0 = 0.f, aA1 = 0.f, aA2 = 0.f, aA3 = 0.f;
        if (q == 0) {
            float eself = head ? esA1 : esA0;
            uint2 hs = hb2[(size_t)gnA * 16 + fl];
            aA0 = eself * bf_lo(hs.x); aA1 = eself * bf_hi(hs.x);
            aA2 = eself * bf_lo(hs.y); aA3 = eself * bf_hi(hs.y);
        }
        float dsA = 0.f;

        // ---- setup B (guarded)
        int begB = 0, cntB = 0;
        float2 advB = make_float2(0.f, 0.f);
        float esB0 = 0.f, esB1 = 0.f;
        float aB0 = 0.f, aB1 = 0.f, aB2 = 0.f, aB3 = 0.f;
        float dsB = 0.f;
        if (vB) {
            begB = lscan[dlB]; cntB = ldeg[dlB];
            advB = ((const float2*)a_dst)[gnB];
            float2 asvB = ((const float2*)a_src)[gnB];
            float tB0 = asvB.x + advB.x; tB0 = tB0 > 0.f ? tB0 : 0.2f * tB0;
            float tB1 = asvB.y + advB.y; tB1 = tB1 > 0.f ? tB1 : 0.2f * tB1;
            esB0 = __expf(tB0); esB1 = __expf(tB1);
            if (q == 0) {
                float eself = head ? esB1 : esB0;
                uint2 hs = hb2[(size_t)gnB * 16 + fl];
                aB0 = eself * bf_lo(hs.x); aB1 = eself * bf_hi(hs.x);
                aB2 = eself * bf_lo(hs.y); aB3 = eself * bf_hi(hs.y);
            }
        }

        int nwA = (cntA + 63) >> 6, nwB = (cntB + 63) >> 6;
        int nwin = nwA > nwB ? nwA : nwB;
        for (int w = 0; w < nwin; ++w) {
            int b0 = w << 6;
            // window A
            u32 siA = (u32)gnA; float eA0 = 0.f, eA1 = 0.f; int wnA = 0;
            if (w < nwA) {
                wnA = cntA - b0; if (wnA > 64) wnA = 64;
                if (lane < wnA) {
                    siA = (u32)st2[begA + b0 + lane];
                    float2 ap = ((const float2*)a_src)[siA];
                    float v0 = ap.x + advA.x; v0 = v0 > 0.f ? v0 : 0.2f * v0;
                    float v1 = ap.y + advA.y; v1 = v1 > 0.f ? v1 : 0.2f * v1;
                    eA0 = __expf(v0); eA1 = __expf(v1);
                }
            }
            // window B
            u32 siB = (u32)gnA; float eB0 = 0.f, eB1 = 0.f; int wnB = 0;
            if (w < nwB) {
                wnB = cntB - b0; if (wnB > 64) wnB = 64;
                if (lane < wnB) {
                    siB = (u32)st2[begB + b0 + lane];
                    float2 ap = ((const float2*)a_src)[siB];
                    float v0 = ap.x + advB.x; v0 = v0 > 0.f ? v0 : 0.2f * v0;
                    float v1 = ap.y + advB.y; v1 = v1 > 0.f ? v1 : 0.2f * v1;
                    eB0 = __expf(v0); eB1 = __expf(v1);
                }
            }
            int wmax = wnA > wnB ? wnA : wnB;
            int iters = (wmax + 3) >> 2;
#pragma unroll 4
            for (int k = 0; k < iters; ++k) {
                int e = 4 * k + q;             // pad lanes carry w=0
                u32 rsiA = __shfl(siA, e, 64);
                u32 rsiB = __shfl(siB, e, 64);
                uint2 hvA = hb2[(size_t)rsiA * 16 + fl];
                uint2 hvB = hb2[(size_t)rsiB * 16 + fl];
                float w0A = __shfl(eA0, e, 64), w1A = __shfl(eA1, e, 64);
                float w0B = __shfl(eB0, e, 64), w1B = __shfl(eB1, e, 64);
                float wA = head ? w1A : w0A;
                float wB = head ? w1B : w0B;
                dsA += wA; dsB += wB;
                aA0 = fmaf(wA, bf_lo(hvA.x), aA0);
                aA1 = fmaf(wA, bf_hi(hvA.x), aA1);
                aA2 = fmaf(wA, bf_lo(hvA.y), aA2);
                aA3 = fmaf(wA, bf_hi(hvA.y), aA3);
                aB0 = fmaf(wB, bf_lo(hvB.x), aB0);
                aB1 = fmaf(wB, bf_hi(hvB.x), aB1);
                aB2 = fmaf(wB, bf_lo(hvB.y), aB2);
                aB3 = fmaf(wB, bf_hi(hvB.y), aB3);
            }
        }
        // reduce over the 4 quarter-groups
        dsA += __shfl_xor(dsA, 16, 64); dsA += __shfl_xor(dsA, 32, 64);
        dsB += __shfl_xor(dsB, 16, 64); dsB += __shfl_xor(dsB, 32, 64);
        aA0 += __shfl_xor(aA0, 16, 64); aA0 += __shfl_xor(aA0, 32, 64);
        aA1 += __shfl_xor(aA1, 16, 64); aA1 += __shfl_xor(aA1, 32, 64);
        aA2 += __shfl_xor(aA2, 16, 64); aA2 += __shfl_xor(aA2, 32, 64);
        aA3 += __shfl_xor(aA3, 16, 64); aA3 += __shfl_xor(aA3, 32, 64);
        aB0 += __shfl_xor(aB0, 16, 64); aB0 += __shfl_xor(aB0, 32, 64);
        aB1 += __shfl_xor(aB1, 16, 64); aB1 += __shfl_xor(aB1, 32, 64);
        aB2 += __shfl_xor(aB2, 16, 64); aB2 += __shfl_xor(aB2, 32, 64);
        aB3 += __shfl_xor(aB3, 16, 64); aB3 += __shfl_xor(aB3, 32, 64);

        if (q == 0) {
            {   // epilogue A
                float den = (head ? esA1 : esA0) + dsA;
                float inv = 1.f / den;
                float cntf = (float)ucnt[dlA];
                float nw = ((float)usum[dlA] * (1.f / 65536.f)) / fmaxf(cntf, 1.f);
                nw = fminf(fmaxf(nw, 0.2f), 5.f);
                float en = sf * (nw - 1.f);
                float4 o;
                o.x = aA0 * inv + bb.x + en;
                o.y = aA1 * inv + bb.y + en;
                o.z = aA2 * inv + bb.z + en;
                o.w = aA3 * inv + bb.w + en;
                ((float4*)out)[(size_t)gnA * 16 + fl] = o;
            }
            if (vB) {   // epilogue B
                float den = (head ? esB1 : esB0) + dsB;
                float inv = 1.f / den;
                float cntf = (float)ucnt[dlB];
                float nw = ((float)usum[dlB] * (1.f / 65536.f)) / fmaxf(cntf, 1.f);
                nw = fminf(fmaxf(nw, 0.2f), 5.f);
                float en = sf * (nw - 1.f);
                float4 o;
                o.x = aB0 * inv + bb.x + en;
                o.y = aB1 * inv + bb.y + en;
                o.z = aB2 * inv + bb.z + en;
                o.w = aB3 * inv + bb.w + en;
                ((float4*)out)[(size_t)gnB * 16 + fl] = o;
            }
        }
    }
}

// ---------------------------------------------------------------- launch
extern "C" void kernel_launch(void* const* d_in, const int* in_sizes, int n_in,
                              void* d_out, int out_size, void* d_ws, size_t ws_size,
                              hipStream_t stream)
{
    const float* x     = (const float*)d_in[0];
    const int*   ei    = (const int*)d_in[1];
    const float* wgt   = (const float*)d_in[2];
    const float* Wm    = (const float*)d_in[3];
    const float* att_s = (const float*)d_in[4];
    const float* att_d = (const float*)d_in[5];
    const float* bias  = (const float*)d_in[6];
    const float* esc   = (const float*)d_in[7];
    float* out = (float*)d_out;

    int nN = in_sizes[0] / 128;
    int E  = in_sizes[2];
    int NB2 = (nN + 63) / 64;         // 782 buckets of 64 nodes

    char* p = (char*)d_ws;
    auto alloc = [&](size_t bytes) -> char* {
        char* r = p; p += (bytes + 255) & ~(size_t)255; return r;
    };
    u32*   hb32  = (u32*)  alloc((size_t)nN * 32 * 4);
    float* a_src = (float*)alloc((size_t)nN * 2 * 4);
    float* a_dst = (float*)alloc((size_t)nN * 2 * 4);
    short* Whf   = (short*)alloc(16 * 64 * 8 * 2);
    short* Wlf   = (short*)alloc(16 * 64 * 8 * 2);
    int*   cursA = (int*)  alloc(NB2_MAX * 4);
    int*   cursB = (int*)  alloc(NB2_MAX * 4);
    u32*   bufA  = (u32*)  alloc((size_t)NB2 * SLOTS2 * 4);
    u32*   bufB  = (u32*)  alloc((size_t)NB2 * SLOTS2 * 4);

    int nblkA = (E + EPB - 1) / EPB;
    int nblkN = (nN + 63) / 64;
    int nblkF = 2 * nblkA + nblkN;

    k_prep<<<dim3(1), dim3(256), 0, stream>>>(Wm, Whf, Wlf, cursA, cursB);
    k_fused<<<dim3(nblkF), dim3(256), 0, stream>>>(x, Whf, Wlf, att_s, att_d,
                                                   hb32, a_src, a_dst,
                                                   ei, wgt, cursA, cursB, bufA, bufB,
                                                   E, NB2, nblkA, nN);
    k_final<<<dim3(NB2), dim3(512), 0, stream>>>(hb32, a_src, a_dst, bufA, cursA,
                                                 bufB, cursB, bias, esc, out, nN);
}